// Round 6
// baseline (244.225 us; speedup 1.0000x reference)
//
#include <hip/hip_runtime.h>

#define NEG_INF_F (-1e30f)
#define MARGIN_F 0.1f
#define TABN 4096
#define BR 64      // rows per block
#define NT 256     // threads per block (4 waves)

// ---- monotone float<->uint key for atomicMax on floats ----
__device__ __forceinline__ unsigned fkey(float f) {
    unsigned b = __float_as_uint(f);
    return (b & 0x80000000u) ? ~b : (b | 0x80000000u);
}
__device__ __forceinline__ float fdec(unsigned k) {
    unsigned b = (k & 0x80000000u) ? (k ^ 0x80000000u) : ~k;
    return __uint_as_float(b);
}

// ============================================================
// Kernel A: setup (1 block). id->bitmask tables, gathered qT,
// init qkeys, accums, barrier counters.
// ============================================================
__global__ __launch_bounds__(256) void setup_kernel(
    const float* __restrict__ inputs_col,
    const int* __restrict__ targets_col,
    const int* __restrict__ qidxs,
    const int* __restrict__ pidxs,
    const int* __restrict__ nnegs,
    unsigned* __restrict__ ptab,    // [TABN]
    unsigned* __restrict__ ntab,    // [TABN]
    float* __restrict__ qT,         // [128][32] k-major
    unsigned* __restrict__ qkeys,   // [32][2]
    float* __restrict__ accums,     // [160]
    unsigned* __restrict__ bar,     // [2]
    int d, int Q, int P, int Nn, int triplet_len)
{
    __shared__ int qmap[32];
    const int tid = threadIdx.x;

    if (tid < Q) {
        int t = targets_col[tid * triplet_len];
        int l = 0;
        for (int i = Q - 1; i >= 0; --i) if (qidxs[i] == t) l = i;  // argmax semantics
        qmap[tid] = l;
    }
    for (int i = tid; i < TABN; i += 256) { ptab[i] = 0u; ntab[i] = 0u; }
    if (tid < 2 * Q) qkeys[tid] = fkey(NEG_INF_F);
    if (tid < 160) accums[tid] = 0.f;
    if (tid < 2) bar[tid] = 0u;
    __syncthreads();

    for (int i = tid; i < Q * P; i += 256) {
        int q = i / P, k = i - q * P;
        int id = pidxs[qmap[q] * P + k];
        if ((unsigned)id < TABN) atomicOr(&ptab[id], 1u << q);
    }
    for (int i = tid; i < Q * Nn; i += 256) {
        int q = i / Nn, k = i - q * Nn;
        int id = nnegs[qmap[q] * Nn + k];
        if ((unsigned)id < TABN) atomicOr(&ntab[id], 1u << q);
    }
    for (int i = tid; i < d * Q; i += 256) {
        int dd = i >> 5, q = i & 31;    // Q == 32
        qT[i] = inputs_col[(size_t)(q * triplet_len) * d + dd];
    }
}

// ============================================================
// Manual grid barrier. Residency: 1024 blocks; capacity/CU:
// LDS 29KB -> 5 blocks, launch_bounds(256,4) -> >=4 blocks by
// VGPR; need 4/CU x 256 CU = 1024. Guaranteed by construction.
// ============================================================
__device__ __forceinline__ void gsync(unsigned* cnt, unsigned nblk) {
    __syncthreads();
    if (threadIdx.x == 0) {
        __threadfence();                 // release
        atomicAdd(cnt, 1u);
        while (__hip_atomic_load(cnt, __ATOMIC_RELAXED, __HIP_MEMORY_SCOPE_AGENT) < nblk)
            __builtin_amdgcn_s_sleep(2);
        __threadfence();                 // acquire
    }
    __syncthreads();
}

// ============================================================
// Fused kernel: 1024 blocks x 256 thr. Per-wave: 16 rows x 32 q,
// k split across lane halves (kh). 8 double-buffered k-chunks of
// 16, loads issued 2 chunks ahead (latency hidden under compute).
//  phase1: dots -> kh-combine -> masked maxes -> atomicMax qkeys
//  gsync
//  phase2: thresholds, selection on register acc -> accums[160]
//  last-block ticket -> finalize -> out[0]
// ============================================================
__global__ __launch_bounds__(NT, 4) void fused_kernel(
    const float* __restrict__ qT,        // [128][32]
    const float* __restrict__ rows,      // [m][128]
    const int* __restrict__ targets_row,
    const unsigned* __restrict__ ptab,
    const unsigned* __restrict__ ntab,
    unsigned* __restrict__ qkeys,        // [32][2]
    float* __restrict__ accums,          // [160]
    unsigned* __restrict__ bar,          // [2]
    float* __restrict__ out,
    int m, int nb)
{
    __shared__ float qv[128][32];        // [k][q] 16KB
    __shared__ float kt[2][16][68];      // [buf][k][row+pad] 8.7KB
    __shared__ unsigned pbm[BR], nbm[BR];
    __shared__ unsigned spk[32], snk[32];
    __shared__ float sthr[2][32];
    __shared__ float wpart[4][32][5];
    __shared__ int islast;

    const int tid  = threadIdx.x;
    const int bid  = blockIdx.x;
    const int j0   = bid * BR;
    const int lane = tid & 63;
    const int wave = tid >> 6;
    const int kh   = lane >> 5;          // k-half
    const int rg   = (lane >> 3) & 3;    // row group (4 rows)
    const int qg   = lane & 7;           // q group (4 qs)
    const int q0   = qg * 4;
    const int rloc = wave * 16 + rg * 4; // row within block tile

    // qv: flat float4 copy (qT is same [k][q] layout)
    for (int i = tid; i < 128 * 32 / 4; i += NT)
        ((float4*)qv)[i] = ((const float4*)qT)[i];
    if (tid < 32) { spk[tid] = fkey(NEG_INF_F); snk[tid] = fkey(NEG_INF_F); }
    if (tid < BR) {
        int j = j0 + tid;
        unsigned pbv = 0u, nbv = 0u;
        if (j < m) {
            int t = targets_row[j];
            if ((unsigned)t < TABN) { pbv = ptab[t]; nbv = ~ntab[t]; }
            else                    { nbv = ~0u; }
        }
        pbm[tid] = pbv; nbm[tid] = nbv;
    }

    // staging ids: thread -> (row sr, float4 sk4); coalesced 64B/row
    const int sr  = tid >> 2;            // 0..63
    const int sk4 = tid & 3;             // 0..3 (16 floats per chunk)
    int jr = j0 + sr; if (jr >= m) jr = m - 1;
    const float* gsrc = rows + (size_t)jr * 128 + sk4 * 4;

    // prologue: chunk0 -> LDS; issue chunk1
    {
        float4 v0 = *(const float4*)(gsrc);
        kt[0][sk4 * 4 + 0][sr] = v0.x;
        kt[0][sk4 * 4 + 1][sr] = v0.y;
        kt[0][sk4 * 4 + 2][sr] = v0.z;
        kt[0][sk4 * 4 + 3][sr] = v0.w;
    }
    float4 vnext = *(const float4*)(gsrc + 16);
    __syncthreads();

    float acc[4][4];
#pragma unroll
    for (int a = 0; a < 4; ++a)
#pragma unroll
        for (int b = 0; b < 4; ++b) acc[a][b] = 0.f;

    for (int c = 0; c < 8; ++c) {
        const int B = c & 1;
#pragma unroll
        for (int s = 0; s < 8; ++s) {
            const int kl = kh * 8 + s;
            float4 qf = *(const float4*)&qv[c * 16 + kl][q0];
            float4 rf = *(const float4*)&kt[B][kl][rloc];
            const float* qp = (const float*)&qf;
            const float* rp = (const float*)&rf;
#pragma unroll
            for (int qi = 0; qi < 4; ++qi)
#pragma unroll
                for (int ri = 0; ri < 4; ++ri)
                    acc[qi][ri] = fmaf(qp[qi], rp[ri], acc[qi][ri]);
        }
        if (c < 7) {
            __syncthreads();             // prev readers of buf B^1 done
            kt[B ^ 1][sk4 * 4 + 0][sr] = vnext.x;
            kt[B ^ 1][sk4 * 4 + 1][sr] = vnext.y;
            kt[B ^ 1][sk4 * 4 + 2][sr] = vnext.z;
            kt[B ^ 1][sk4 * 4 + 3][sr] = vnext.w;
            if (c < 6) vnext = *(const float4*)(gsrc + (c + 2) * 16);
            __syncthreads();             // buf B^1 ready
        }
    }

    // combine k-halves: both halves end with full dots
#pragma unroll
    for (int qi = 0; qi < 4; ++qi)
#pragma unroll
        for (int ri = 0; ri < 4; ++ri)
            acc[qi][ri] += __shfl_xor(acc[qi][ri], 32);

    unsigned pb[4], nbr[4];
#pragma unroll
    for (int r = 0; r < 4; ++r) { pb[r] = pbm[rloc + r]; nbr[r] = nbm[rloc + r]; }

    // masked maxes: reduce rg (strides 8,16) within each half
#pragma unroll
    for (int qi = 0; qi < 4; ++qi) {
        const int q = q0 + qi;
        float pmax = NEG_INF_F, nmax = NEG_INF_F;
#pragma unroll
        for (int r = 0; r < 4; ++r) {
            if ((pb[r] >> q) & 1u)  pmax = fmaxf(pmax, acc[qi][r]);
            if ((nbr[r] >> q) & 1u) nmax = fmaxf(nmax, acc[qi][r]);
        }
        pmax = fmaxf(pmax, __shfl_down(pmax, 8));
        pmax = fmaxf(pmax, __shfl_down(pmax, 16));
        nmax = fmaxf(nmax, __shfl_down(nmax, 8));
        nmax = fmaxf(nmax, __shfl_down(nmax, 16));
        if (lane < 8) {                  // kh=0, rg=0 lanes hold wave max
            atomicMax(&spk[q], fkey(pmax));
            atomicMax(&snk[q], fkey(nmax));
        }
    }
    __syncthreads();
    if (tid < 64) {
        int side = tid >> 5, q = tid & 31;
        atomicMax(&qkeys[q * 2 + side], side ? snk[q] : spk[q]);
    }

    gsync(&bar[0], (unsigned)nb);

    // ---- phase 2: thresholds ----
    if (tid < 64) {
        int side = tid >> 5, q = tid & 31;
        sthr[side][q] = fdec(qkeys[q * 2 + side]);
    }
    __syncthreads();

    // selection on register acc (kh halves duplicate -> count kh0 only)
#pragma unroll
    for (int qi = 0; qi < 4; ++qi) {
        const int q = q0 + qi;
        const float posThr = sthr[1][q] + MARGIN_F;               // s < neg_max + margin
        const float negThr = fmaxf(0.4f, sthr[0][q]) - MARGIN_F;  // s > max(0.4,pos_max) - margin
        float ps = 0.f, pc = 0.f, ns = 0.f, nc = 0.f, pmc = 0.f;
#pragma unroll
        for (int r = 0; r < 4; ++r) {
            float s = acc[qi][r];
            unsigned pm = (pb[r] >> q) & 1u;
            unsigned nm = (nbr[r] >> q) & 1u;
            pmc += (float)pm;
            if (pm && s < posThr) { ps += 1.f - s; pc += 1.f; }
            if (nm && s > negThr) { ns += s;       nc += 1.f; }
        }
        ps  += __shfl_down(ps, 8);  ps  += __shfl_down(ps, 16);
        pc  += __shfl_down(pc, 8);  pc  += __shfl_down(pc, 16);
        ns  += __shfl_down(ns, 8);  ns  += __shfl_down(ns, 16);
        nc  += __shfl_down(nc, 8);  nc  += __shfl_down(nc, 16);
        pmc += __shfl_down(pmc, 8); pmc += __shfl_down(pmc, 16);
        if (lane < 8) {                  // kh0 only: single count
            wpart[wave][lane * 4 + qi][0] = ps;
            wpart[wave][lane * 4 + qi][1] = pc;
            wpart[wave][lane * 4 + qi][2] = ns;
            wpart[wave][lane * 4 + qi][3] = nc;
            wpart[wave][lane * 4 + qi][4] = pmc;
        }
    }
    __syncthreads();
    if (tid < 160) {
        float v = 0.f;
#pragma unroll
        for (int w = 0; w < 4; ++w) v += wpart[w][tid / 5][tid % 5];
        atomicAdd(&accums[tid], v);
    }

    // ---- last-block finalize ----
    __syncthreads();
    if (tid == 0) {
        __threadfence();
        unsigned old = atomicAdd(&bar[1], 1u);
        islast = (old == (unsigned)(nb - 1)) ? 1 : 0;
    }
    __syncthreads();
    if (islast) {
        if (tid == 0) __threadfence();
        __syncthreads();
        if (tid < 64) {
            float v = 0.f;
            if (tid < 32) {
                float psv = accums[tid * 5 + 0];
                float pcv = accums[tid * 5 + 1];
                float nsv = accums[tid * 5 + 2];
                float ncv = accums[tid * 5 + 3];
                float pmc = accums[tid * 5 + 4];
                float pl = (pcv > 0.f) ? psv / pcv : 0.f;
                float nl = (ncv > 0.f) ? nsv / ncv : 0.f;
                v = (pmc > 0.f) ? (pl + nl) : 0.f;
            }
#pragma unroll
            for (int off = 32; off; off >>= 1) v += __shfl_down(v, off);
            if (tid == 0) out[0] = v / 32.0f;
        }
    }
}

// ============================================================
extern "C" void kernel_launch(void* const* d_in, const int* in_sizes, int n_in,
                              void* d_out, int out_size, void* d_ws, size_t ws_size,
                              hipStream_t stream)
{
    const float* inputs_col = (const float*)d_in[0];
    const float* inputs_row = (const float*)d_in[1];
    const int* targets_col  = (const int*)d_in[2];
    const int* targets_row  = (const int*)d_in[3];
    const int* qidxs        = (const int*)d_in[4];
    const int* pidxs        = (const int*)d_in[5];
    const int* nnegs        = (const int*)d_in[6];

    const int n  = in_sizes[2];
    int m        = in_sizes[3];
    const int Q  = in_sizes[4];            // 32
    const int P  = in_sizes[5] / Q;        // 10
    const int Nn = in_sizes[6] / Q;        // 25
    const int d  = in_sizes[0] / n;        // 128
    const int triplet_len = n / Q;         // 12

    int nb = (m + BR - 1) / BR;            // 1024

    char* ws = (char*)d_ws;
    size_t off = 0;
    unsigned* ptab  = (unsigned*)(ws + off); off += (size_t)TABN * 4;
    unsigned* ntab  = (unsigned*)(ws + off); off += (size_t)TABN * 4;
    float* qT       = (float*)(ws + off);    off += (size_t)d * Q * 4;
    unsigned* qkeys = (unsigned*)(ws + off); off += (size_t)Q * 2 * 4;
    float* accums   = (float*)(ws + off);    off += (size_t)160 * 4;
    unsigned* bar   = (unsigned*)(ws + off); off += 2 * 4;
    float* out      = (float*)d_out;

    setup_kernel<<<1, 256, 0, stream>>>(inputs_col, targets_col, qidxs, pidxs, nnegs,
                                        ptab, ntab, qT, qkeys, accums, bar,
                                        d, Q, P, Nn, triplet_len);

    fused_kernel<<<nb, NT, 0, stream>>>(qT, inputs_row, targets_row, ptab, ntab,
                                        qkeys, accums, bar, out, m, nb);
}

// Round 7
// 186.776 us; speedup vs baseline: 1.3076x; 1.3076x over previous
//
#include <hip/hip_runtime.h>

#define NEG_INF_F (-1e30f)
#define MARGIN_F 0.1f
#define TABN 4096
#define BR 256     // rows per block
#define NT 512     // threads per block (8 waves)

// ---- monotone float<->uint key for LDS atomicMax on floats ----
__device__ __forceinline__ unsigned fkey(float f) {
    unsigned b = __float_as_uint(f);
    return (b & 0x80000000u) ? ~b : (b | 0x80000000u);
}
__device__ __forceinline__ float fdec(unsigned k) {
    unsigned b = (k & 0x80000000u) ? (k ^ 0x80000000u) : ~k;
    return __uint_as_float(b);
}

// ============================================================
// Kernel A: setup (1 block). id->bitmask tables, gathered qT,
// zero barrier words.
// ============================================================
__global__ __launch_bounds__(256) void setup_kernel(
    const float* __restrict__ inputs_col,
    const int* __restrict__ targets_col,
    const int* __restrict__ qidxs,
    const int* __restrict__ pidxs,
    const int* __restrict__ nnegs,
    unsigned* __restrict__ ptab,    // [TABN]
    unsigned* __restrict__ ntab,    // [TABN]
    float* __restrict__ qT,         // [128][32] k-major
    unsigned* __restrict__ bar,     // [96]: cnt@0, flag@32, ticket@64
    int d, int Q, int P, int Nn, int triplet_len)
{
    __shared__ int qmap[32];
    const int tid = threadIdx.x;

    if (tid < Q) {
        int t = targets_col[tid * triplet_len];
        int l = 0;
        for (int i = Q - 1; i >= 0; --i) if (qidxs[i] == t) l = i;  // argmax semantics
        qmap[tid] = l;
    }
    for (int i = tid; i < TABN; i += 256) { ptab[i] = 0u; ntab[i] = 0u; }
    if (tid < 96) bar[tid] = 0u;
    __syncthreads();

    for (int i = tid; i < Q * P; i += 256) {
        int q = i / P, k = i - q * P;
        int id = pidxs[qmap[q] * P + k];
        if ((unsigned)id < TABN) atomicOr(&ptab[id], 1u << q);
    }
    for (int i = tid; i < Q * Nn; i += 256) {
        int q = i / Nn, k = i - q * Nn;
        int id = nnegs[qmap[q] * Nn + k];
        if ((unsigned)id < TABN) atomicOr(&ntab[id], 1u << q);
    }
    for (int i = tid; i < d * Q; i += 256) {
        int dd = i >> 5, q = i & 31;    // Q == 32
        qT[i] = inputs_col[(size_t)(q * triplet_len) * d + dd];
    }
}

// ============================================================
// Sense-reversing grid barrier: arrivals add to cnt (no readers
// -> line stays exclusive, adds pipeline); spinners poll a
// DIFFERENT cacheline (flag) written once by the last arriver.
// Residency: 256 blocks, capacity >=2 blocks/CU x 256 CUs.
// ============================================================
__device__ __forceinline__ void gsync(unsigned* cnt, unsigned* flag, unsigned nblk) {
    __syncthreads();
    if (threadIdx.x == 0) {
        __threadfence();                 // release: my stores visible
        unsigned old = atomicAdd(cnt, 1u);
        if (old == nblk - 1u) {
            __hip_atomic_store(flag, 1u, __ATOMIC_RELEASE, __HIP_MEMORY_SCOPE_AGENT);
        } else {
            while (__hip_atomic_load(flag, __ATOMIC_RELAXED, __HIP_MEMORY_SCOPE_AGENT) == 0u)
                __builtin_amdgcn_s_sleep(8);
        }
        __threadfence();                 // acquire: invalidate stale caches
    }
    __syncthreads();
}

// ============================================================
// Fused kernel: 256 blocks x 512 thr (1/CU). Per-thread 4q x 4r.
// Rows staged in 8-k double-buffered LDS chunks, 1 chunk ahead.
//  phase1: dots -> block masked maxes -> PLAIN stores gmax[64][nb]
//  gsync (sense-reversing)
//  phase2: every block scans gmax -> thresholds; selection on
//          register acc -> block partials -> PLAIN stores psum
//  ticket (1 atomic/block) -> last block reduces psum -> out[0]
// ============================================================
__global__ __launch_bounds__(NT, 4) void fused_kernel(
    const float* __restrict__ qT,        // [128][32]
    const float* __restrict__ rows,      // [m][128]
    const int* __restrict__ targets_row,
    const unsigned* __restrict__ ptab,
    const unsigned* __restrict__ ntab,
    float* __restrict__ gmax,            // [64][nb]  pair = side*32+q
    float* __restrict__ psum,            // [nb][160]
    unsigned* __restrict__ bar,          // [96]
    float* __restrict__ out,
    int m, int nb)
{
    __shared__ float qv[128][32];        // [k][q] 16KB
    __shared__ float kt[2][8][264];      // [buf][k][row+pad] 16.9KB
    __shared__ unsigned pbm[BR], nbm[BR];
    __shared__ unsigned spk[32], snk[32];
    __shared__ float sthr[2][32];
    __shared__ float wpart[8][32][5];
    __shared__ float fin[160];
    __shared__ int islast;

    const int tid  = threadIdx.x;
    const int bid  = blockIdx.x;
    const int j0   = bid * BR;
    const int lane = tid & 63;
    const int wave = tid >> 6;           // 0..7
    const int qg   = lane & 7, q0 = qg * 4;
    const int rgl  = lane >> 3;          // 0..7
    const int rloc = wave * 32 + rgl * 4;

    // stage qv (flat float4 copy; same [k][q] layout)
    for (int i = tid; i < 128 * 32 / 4; i += NT)
        ((float4*)qv)[i] = ((const float4*)qT)[i];
    if (tid < 32) { spk[tid] = fkey(NEG_INF_F); snk[tid] = fkey(NEG_INF_F); }
    if (tid < BR) {
        int j = j0 + tid;
        unsigned pbv = 0u, nbv = 0u;
        if (j < m) {
            int t = targets_row[j];
            if ((unsigned)t < TABN) { pbv = ptab[t]; nbv = ~ntab[t]; }
            else                    { nbv = ~0u; }
        }
        pbm[tid] = pbv; nbm[tid] = nbv;
    }

    // staging: thread -> (row sr, float4-slot k4); 8-k chunk = 512 float4
    const int sr  = tid >> 1;            // 0..255
    const int k4  = tid & 1;             // 0..1
    int jr = j0 + sr; if (jr >= m) jr = m - 1;
    const float* gsrc = rows + (size_t)jr * 128 + k4 * 4;

    // prologue: chunk0 -> buf0; issue chunk1
    {
        float4 v = *(const float4*)(gsrc);
        kt[0][k4 * 4 + 0][sr] = v.x;
        kt[0][k4 * 4 + 1][sr] = v.y;
        kt[0][k4 * 4 + 2][sr] = v.z;
        kt[0][k4 * 4 + 3][sr] = v.w;
    }
    float4 vnext = *(const float4*)(gsrc + 8);
    __syncthreads();

    float acc[4][4];
#pragma unroll
    for (int a = 0; a < 4; ++a)
#pragma unroll
        for (int b = 0; b < 4; ++b) acc[a][b] = 0.f;

    for (int c = 0; c < 16; ++c) {
        const int B = c & 1;
#pragma unroll
        for (int s = 0; s < 8; ++s) {
            float4 qf = *(const float4*)&qv[c * 8 + s][q0];
            float4 rf = *(const float4*)&kt[B][s][rloc];
            const float* qp = (const float*)&qf;
            const float* rp = (const float*)&rf;
#pragma unroll
            for (int qi = 0; qi < 4; ++qi)
#pragma unroll
                for (int ri = 0; ri < 4; ++ri)
                    acc[qi][ri] = fmaf(qp[qi], rp[ri], acc[qi][ri]);
        }
        if (c < 15) {
            __syncthreads();             // all readers of buf B^1 done
            kt[B ^ 1][k4 * 4 + 0][sr] = vnext.x;
            kt[B ^ 1][k4 * 4 + 1][sr] = vnext.y;
            kt[B ^ 1][k4 * 4 + 2][sr] = vnext.z;
            kt[B ^ 1][k4 * 4 + 3][sr] = vnext.w;
            if (c < 14) vnext = *(const float4*)(gsrc + (c + 2) * 8);
            __syncthreads();             // buf B^1 ready
        }
    }

    unsigned pb[4], nbr[4];
#pragma unroll
    for (int r = 0; r < 4; ++r) { pb[r] = pbm[rloc + r]; nbr[r] = nbm[rloc + r]; }

    // block masked maxes -> LDS -> plain stores to gmax
#pragma unroll
    for (int qi = 0; qi < 4; ++qi) {
        const int q = q0 + qi;
        float pmax = NEG_INF_F, nmax = NEG_INF_F;
#pragma unroll
        for (int r = 0; r < 4; ++r) {
            if ((pb[r] >> q) & 1u)  pmax = fmaxf(pmax, acc[qi][r]);
            if ((nbr[r] >> q) & 1u) nmax = fmaxf(nmax, acc[qi][r]);
        }
#pragma unroll
        for (int off = 32; off >= 8; off >>= 1) {
            pmax = fmaxf(pmax, __shfl_down(pmax, off));
            nmax = fmaxf(nmax, __shfl_down(nmax, off));
        }
        if (lane < 8) {                  // lane == qg holds wave max
            atomicMax(&spk[q], fkey(pmax));
            atomicMax(&snk[q], fkey(nmax));
        }
    }
    __syncthreads();
    if (tid < 64) {
        int side = tid >> 5, q = tid & 31;
        gmax[(size_t)tid * nb + bid] = fdec(side ? snk[q] : spk[q]);
    }

    gsync(&bar[0], &bar[32], (unsigned)nb);

    // ---- phase 2: thresholds from gmax scan ----
    {
        int p = tid >> 3, c = tid & 7;   // 64 pairs x 8 scanners
        float mv = NEG_INF_F;
        for (int b = c; b < nb; b += 8) mv = fmaxf(mv, gmax[(size_t)p * nb + b]);
#pragma unroll
        for (int msk = 1; msk <= 4; msk <<= 1) mv = fmaxf(mv, __shfl_xor(mv, msk));
        if (c == 0) sthr[p >> 5][p & 31] = mv;
    }
    __syncthreads();

    // selection on register acc -> block partials
#pragma unroll
    for (int qi = 0; qi < 4; ++qi) {
        const int q = q0 + qi;
        const float posThr = sthr[1][q] + MARGIN_F;               // s < neg_max + margin
        const float negThr = fmaxf(0.4f, sthr[0][q]) - MARGIN_F;  // s > max(0.4,pos_max) - margin
        float ps = 0.f, pc = 0.f, ns = 0.f, nc = 0.f, pmc = 0.f;
#pragma unroll
        for (int r = 0; r < 4; ++r) {
            float s = acc[qi][r];
            unsigned pm = (pb[r] >> q) & 1u;
            unsigned nm = (nbr[r] >> q) & 1u;
            pmc += (float)pm;
            if (pm && s < posThr) { ps += 1.f - s; pc += 1.f; }
            if (nm && s > negThr) { ns += s;       nc += 1.f; }
        }
#pragma unroll
        for (int off = 32; off >= 8; off >>= 1) {
            ps  += __shfl_down(ps, off);
            pc  += __shfl_down(pc, off);
            ns  += __shfl_down(ns, off);
            nc  += __shfl_down(nc, off);
            pmc += __shfl_down(pmc, off);
        }
        if (lane < 8) {
            wpart[wave][lane * 4 + qi][0] = ps;
            wpart[wave][lane * 4 + qi][1] = pc;
            wpart[wave][lane * 4 + qi][2] = ns;
            wpart[wave][lane * 4 + qi][3] = nc;
            wpart[wave][lane * 4 + qi][4] = pmc;
        }
    }
    __syncthreads();
    if (tid < 160) {
        float v = 0.f;
#pragma unroll
        for (int w = 0; w < 8; ++w) v += wpart[w][tid / 5][tid % 5];
        psum[(size_t)bid * 160 + tid] = v;   // plain store
    }

    // ---- ticket + last-block finalize ----
    __syncthreads();
    if (tid == 0) {
        __threadfence();
        unsigned old = atomicAdd(&bar[64], 1u);
        islast = (old == (unsigned)(nb - 1)) ? 1 : 0;
    }
    __syncthreads();
    if (islast) {
        if (tid == 0) __threadfence();
        __syncthreads();
        if (tid < 160) {
            float v = 0.f;
            for (int b = 0; b < nb; ++b) v += psum[(size_t)b * 160 + tid];
            fin[tid] = v;
        }
        __syncthreads();
        if (tid < 64) {
            float v = 0.f;
            if (tid < 32) {
                float psv = fin[tid * 5 + 0];
                float pcv = fin[tid * 5 + 1];
                float nsv = fin[tid * 5 + 2];
                float ncv = fin[tid * 5 + 3];
                float pmc = fin[tid * 5 + 4];
                float pl = (pcv > 0.f) ? psv / pcv : 0.f;
                float nl = (ncv > 0.f) ? nsv / ncv : 0.f;
                v = (pmc > 0.f) ? (pl + nl) : 0.f;
            }
#pragma unroll
            for (int off = 32; off; off >>= 1) v += __shfl_down(v, off);
            if (tid == 0) out[0] = v / 32.0f;
        }
    }
}

// ============================================================
extern "C" void kernel_launch(void* const* d_in, const int* in_sizes, int n_in,
                              void* d_out, int out_size, void* d_ws, size_t ws_size,
                              hipStream_t stream)
{
    const float* inputs_col = (const float*)d_in[0];
    const float* inputs_row = (const float*)d_in[1];
    const int* targets_col  = (const int*)d_in[2];
    const int* targets_row  = (const int*)d_in[3];
    const int* qidxs        = (const int*)d_in[4];
    const int* pidxs        = (const int*)d_in[5];
    const int* nnegs        = (const int*)d_in[6];

    const int n  = in_sizes[2];
    int m        = in_sizes[3];
    const int Q  = in_sizes[4];            // 32
    const int P  = in_sizes[5] / Q;        // 10
    const int Nn = in_sizes[6] / Q;        // 25
    const int d  = in_sizes[0] / n;        // 128
    const int triplet_len = n / Q;         // 12

    int nb = (m + BR - 1) / BR;            // 256

    char* ws = (char*)d_ws;
    size_t off = 0;
    unsigned* ptab = (unsigned*)(ws + off); off += (size_t)TABN * 4;
    unsigned* ntab = (unsigned*)(ws + off); off += (size_t)TABN * 4;
    float* qT      = (float*)(ws + off);    off += (size_t)d * Q * 4;
    unsigned* bar  = (unsigned*)(ws + off); off += 96 * 4;
    float* gmax    = (float*)(ws + off);    off += (size_t)64 * nb * 4;
    float* psum    = (float*)(ws + off);    off += (size_t)nb * 160 * 4;
    float* out     = (float*)d_out;

    setup_kernel<<<1, 256, 0, stream>>>(inputs_col, targets_col, qidxs, pidxs, nnegs,
                                        ptab, ntab, qT, bar,
                                        d, Q, P, Nn, triplet_len);

    fused_kernel<<<nb, NT, 0, stream>>>(qT, inputs_row, targets_row, ptab, ntab,
                                        gmax, psum, bar, out, m, nb);
}